// Round 9
// baseline (6148.018 us; speedup 1.0000x reference)
//
#include <hip/hip_runtime.h>

typedef __bf16 bf16x8 __attribute__((ext_vector_type(8)));
typedef float f32x4 __attribute__((ext_vector_type(4)));
typedef unsigned short u16;
typedef unsigned long long u64;

#define NSTEP 512

#define AL(p)   __hip_atomic_load((p), __ATOMIC_RELAXED, __HIP_MEMORY_SCOPE_AGENT)
#define AS(p,v) __hip_atomic_store((p), (v), __ATOMIC_RELAXED, __HIP_MEMORY_SCOPE_AGENT)

__device__ __forceinline__ u16 f2bf(float f) {
  union { float f; unsigned u; } x; x.f = f;
  return (u16)((x.u + 0x7fffu + ((x.u >> 16) & 1u)) >> 16);
}

// zero h buffer 0 + barrier flags (runs every call -> deterministic replays)
__global__ void prep_kernel(u16* __restrict__ h0, int* __restrict__ bar) {
  int i = blockIdx.x * blockDim.x + threadIdx.x;
  if (i < 65536) h0[i] = 0;
  if (i < 16416) bar[i] = 0;
}

// A1[t*64+b][512] bf16 embedding gather
__global__ void gather_kernel(const int* __restrict__ sent, const float* __restrict__ emb,
                              u16* __restrict__ A1) {
  int row = blockIdx.x * 4 + (threadIdx.x >> 6);   // t*64+b
  int lane = threadIdx.x & 63;
  int t = row >> 6, b = row & 63;
  int idx = sent[b * 512 + t];
  const float* src = emb + (size_t)idx * 512 + lane * 8;
  u16* dst = A1 + (size_t)row * 512 + lane * 8;
  #pragma unroll
  for (int k = 0; k < 8; ++k) dst[k] = f2bf(src[k]);
}

// 256 WGs x 512 thr (2 WGs/CU, 4 waves/SIMD). WG j: h cols [j*4,j*4+4), gates
// packed rb = g*4+nn = lr. Waves (kh, bt): kh=0 -> x-proj + h-K[0,256) +
// activations/state/store; kh=1 -> h-K[256,1024) + barrier polling.
// Partial accs combined via LDS. Weights in padded LDS; h via agent atomics.
__global__ void __launch_bounds__(512, 2)
lstm_kernel(const u16* __restrict__ A1,
            const float* __restrict__ wih, const float* __restrict__ whh,
            const float* __restrict__ bih, const float* __restrict__ bhh,
            u16* __restrict__ h3, float* __restrict__ out, int* __restrict__ bar) {
  __shared__ u16 wlds[48 * 16 * 36];        // 55296 B, stride-36 pad
  __shared__ float cmb[4][16][16];          // kh1 -> kh0 partial-acc bounce
  __shared__ alignas(8) u16 hx[4][16][4];   // h-store packing bounce

  const int j   = blockIdx.x;
  const int tid = threadIdx.x;
  const int w8  = tid >> 6;            // wave 0..7
  const int kh  = w8 >> 2;             // K-half: 0 = x + h[0,256), 1 = h[256,1024)
  const int bt  = w8 & 3;              // batch tile
  const int l   = tid & 63;
  const int lr  = l & 15, lk = l >> 4;
  const int g   = lr >> 2, nn = lr & 3;
  const int wrow = g * 1024 + j * 4 + nn;

  // ---- stage ALL weights fp32->bf16 into padded LDS (once) ----
  for (int task = tid; task < 3072; task += 512) {
    int kk = task >> 6;                 // K chunk of 32 (0..47)
    int rem = task & 63;
    int rb = rem >> 2, q = rem & 3;
    int row = (rb >> 2) * 1024 + j * 4 + (rb & 3);
    const float* src = (kk < 16) ? (wih + (size_t)row * 512 + kk * 32 + q * 8)
                                 : (whh + (size_t)row * 1024 + (kk - 16) * 32 + q * 8);
    u16* dst = wlds + (kk * 16 + rb) * 36 + q * 8;
    #pragma unroll
    for (int e = 0; e < 8; ++e) dst[e] = f2bf(src[e]);
  }
  __syncthreads();

  const float bias = bih[wrow] + bhh[wrow];
  const float sca = (g == 2) ? 2.f : 1.f;   // tanh-as-sigmoid scaling
  const float bd  = (g == 2) ? -1.f : 0.f;
  const int arow = bt * 16 + lr;            // batch row for A fragments
  const u16* bx = wlds + lr * 36 + lk * 8;  // + kk*576 per K chunk

  float cst[4] = {0.f, 0.f, 0.f, 0.f};

  // kh0: prefetch A1 fragments for t=0
  bf16x8 ax[16];
  if (kh == 0) {
    const u16* apre = A1 + (size_t)arow * 512 + lk * 8;
    #pragma unroll
    for (int kk = 0; kk < 16; ++kk) ax[kk] = *(const bf16x8*)(apre + kk * 32);
  }

  union AF { bf16x8 v; u64 q[2]; };

#define LD8(BUF, CH)                                                        \
  { _Pragma("unroll")                                                       \
    for (int r = 0; r < 8; ++r) {                                           \
      u64* p = (u64*)(hp + (CH) * 256 + r * 32);                            \
      BUF[r].q[0] = AL(p); BUF[r].q[1] = AL(p + 1);                         \
    } }
#define MM8(BUF, W0)                                                        \
  { _Pragma("unroll")                                                       \
    for (int r = 0; r < 8; ++r) {                                           \
      bf16x8 b = *(const bf16x8*)(bx + ((W0) + r) * 576);                   \
      acc = __builtin_amdgcn_mfma_f32_16x16x32_bf16(BUF[r].v, b, acc, 0, 0, 0); \
    } }

  #pragma unroll 1
  for (int t = 0; t < NSTEP; ++t) {
    const u16* hp = h3 + (size_t)(t % 3) * 65536 + (size_t)arow * 1024 + lk * 8;
    AF ha[8], hb[8];
    f32x4 acc;
    if (kh == 0) {
      // x-projection (K=512) + h-K [0,256)
      LD8(ha, 0);
      acc[0] = bias; acc[1] = bias; acc[2] = bias; acc[3] = bias;
      #pragma unroll
      for (int kk = 0; kk < 16; ++kk) {
        bf16x8 b = *(const bf16x8*)(bx + kk * 576);
        acc = __builtin_amdgcn_mfma_f32_16x16x32_bf16(ax[kk], b, acc, 0, 0, 0);
      }
      MM8(ha, 16);
    } else {
      // h-K [256,1024)
      LD8(ha, 1); LD8(hb, 2);
      acc[0] = 0.f; acc[1] = 0.f; acc[2] = 0.f; acc[3] = 0.f;
      MM8(ha, 24);
      LD8(ha, 3);
      MM8(hb, 32);
      MM8(ha, 40);
      // publish partials for the combine
      #pragma unroll
      for (int r = 0; r < 4; ++r) cmb[bt][lk * 4 + r][lr] = acc[r];
    }
    __syncthreads();

    if (kh == 0) {
      float hv4[4], cn4[4];
      #pragma unroll
      for (int r = 0; r < 4; ++r) {
        float xv = acc[r] + cmb[bt][lk * 4 + r][lr];
        float act = sca / (1.f + __expf(-sca * xv)) + bd;  // sigmoid / tanh
        float gg = __shfl_xor(act, 8);
        float ff = __shfl_xor(act, 4);
        float oo = __shfl_xor(act, 12);
        float cn = ff * cst[r] + act * gg;   // act = i at lanes lr<4
        cst[r] = cn;
        float tc = 2.f / (1.f + __expf(-2.f * cn)) - 1.f;
        hv4[r] = oo * tc;
        cn4[r] = cn;
      }
      if (t == NSTEP - 1) {
        if (lr < 4) {
          #pragma unroll
          for (int r = 0; r < 4; ++r) {
            int R = bt * 16 + lk * 4 + r;
            out[(size_t)R * 1024 + j * 4 + lr]          = hv4[r];
            out[65536 + (size_t)R * 1024 + j * 4 + lr]  = hv4[r];
            out[131072 + (size_t)R * 1024 + j * 4 + lr] = cn4[r];
          }
        }
      } else if (lr < 4) {
        #pragma unroll
        for (int r = 0; r < 4; ++r) hx[bt][lk * 4 + r][lr] = f2bf(hv4[r]);
      }
    }
    if (t == NSTEP - 1) break;

    __syncthreads();
    // kh0 waves: one 8B agent-scope store per row
    if (kh == 0 && l < 16) {
      u64 pk = *(const u64*)(&hx[bt][l][0]);
      u16* hw = h3 + (size_t)((t + 1) % 3) * 65536 + (size_t)(bt * 16 + l) * 1024 + j * 4;
      AS((u64*)hw, pk);
    }
    // h stores reach coherence point before the arrival flag
    asm volatile("s_waitcnt vmcnt(0)" ::: "memory");
    __syncthreads();
    const int t1 = t + 1;
    if (tid == 0) AS(&bar[j * 32], t1);          // publish epoch (monotonic)
    if (kh == 0) {
      // prefetch A1 for t+1; latency hides under the barrier window
      const u16* apre = A1 + ((size_t)t1 * 64 + arow) * 512 + lk * 8;
      #pragma unroll
      for (int kk = 0; kk < 16; ++kk) ax[kk] = *(const bf16x8*)(apre + kk * 32);
    } else {
      // kh1 threads: direct all-to-all wait, one poller per producer flag
      while (AL(&bar[(tid - 256) * 32]) < t1) __builtin_amdgcn_s_sleep(1);
    }
    __syncthreads();
  }
#undef LD8
#undef MM8
}

extern "C" void kernel_launch(void* const* d_in, const int* in_sizes, int n_in,
                              void* d_out, int out_size, void* d_ws, size_t ws_size,
                              hipStream_t stream) {
  const int*   sent = (const int*)d_in[0];
  const float* emb  = (const float*)d_in[1];
  const float* w_ih = (const float*)d_in[2];
  const float* w_hh = (const float*)d_in[3];
  const float* b_ih = (const float*)d_in[4];
  const float* b_hh = (const float*)d_in[5];
  float* out = (float*)d_out;

  char* ws = (char*)d_ws;
  u16* A1 = (u16*)ws;                            // 32 MiB
  u16* h3 = (u16*)(ws + 33554432);               // 3 x 128 KiB triple-buffered h
  int* bar = (int*)(ws + 33554432 + 393216);     // 256 epoch flags, 128B stride

  prep_kernel<<<256, 256, 0, stream>>>(h3, bar);
  gather_kernel<<<8192, 256, 0, stream>>>(sent, emb, A1);

  void* args[] = { (void*)&A1, (void*)&w_ih, (void*)&w_hh,
                   (void*)&b_ih, (void*)&b_hh, (void*)&h3, (void*)&out, (void*)&bar };
  hipError_t err = hipLaunchCooperativeKernel((void*)lstm_kernel, dim3(256), dim3(512),
                                              args, 0, stream);
  if (err != hipSuccess) {
    // custom barrier (no cg grid.sync): plain launch is fine when all 256 WGs
    // are co-resident, which the 2-blocks/CU resource envelope guarantees
    lstm_kernel<<<dim3(256), dim3(512), 0, stream>>>(A1, w_ih, w_hh, b_ih, b_hh,
                                                     h3, out, bar);
  }
}